// Round 4
// baseline (134.923 us; speedup 1.0000x reference)
//
#include <hip/hip_runtime.h>

#define D_MODEL 256
#define N_HEADS 8
#define D_HEAD 32
#define MAXN 192   // max neighbors/row; Poisson(32), max over 4096 rows ~60

typedef __attribute__((ext_vector_type(8))) short bf16x8;
typedef __attribute__((ext_vector_type(4))) float f32x4;

__device__ __forceinline__ unsigned short f2bf(float f) {
    union { float f; unsigned int u; } v; v.f = f;
    unsigned int r = v.u + 0x7fff + ((v.u >> 16) & 1);   // RNE
    return (unsigned short)(r >> 16);
}
__device__ __forceinline__ float bf2f(unsigned short u) {
    union { unsigned int u; float f; } v; v.u = ((unsigned int)u) << 16;
    return v.f;
}
__device__ __forceinline__ void pack8(const float* __restrict__ p, short* __restrict__ dst) {
    float4 u0 = *(const float4*)p;
    float4 u1 = *(const float4*)(p + 4);
    ushort4 a, b;
    a.x = f2bf(u0.x); a.y = f2bf(u0.y); a.z = f2bf(u0.z); a.w = f2bf(u0.w);
    b.x = f2bf(u1.x); b.y = f2bf(u1.y); b.z = f2bf(u1.z); b.w = f2bf(u1.w);
    *(ushort4*)dst = a;
    *(ushort4*)(dst + 4) = b;
}

// ---------------------------------------------------------------------------
// Mask: bit (dst,src) set => src attendable from dst. mask pre-zeroed by memset.
// Diagonal folded in (threads e < n).
// ---------------------------------------------------------------------------
__global__ void set_edges_kernel(const int* __restrict__ ei,
                                 unsigned long long* __restrict__ mask,
                                 int E, int n) {
    int e = blockIdx.x * blockDim.x + threadIdx.x;
    int wpr = n >> 6;
    if (e < n)
        atomicOr(&mask[(size_t)e * wpr + (e >> 6)], 1ULL << (e & 63));
    if (e < E) {
        int src = ei[e];
        int dst = ei[E + e];
        atomicOr(&mask[(size_t)dst * wpr + (src >> 6)], 1ULL << (src & 63));
    }
}

// ---------------------------------------------------------------------------
// QKV GEMM, fp32 inputs converted inline to bf16: C = x @ W^T (bf16 out).
// BM=128, BN=64, BK=64, 256 thr = 4 waves, each wave 64x32 (4x2 MFMA tiles).
// ---------------------------------------------------------------------------
__global__ __launch_bounds__(256) void gemm_qkv_kernel(
        const float* __restrict__ x,
        const float* __restrict__ Wq, const float* __restrict__ Wk,
        const float* __restrict__ Wv,
        unsigned short* __restrict__ Qb, unsigned short* __restrict__ Kb,
        unsigned short* __restrict__ Vb) {
    const float* B = (blockIdx.z == 0) ? Wq : (blockIdx.z == 1) ? Wk : Wv;
    unsigned short* Cb = (blockIdx.z == 0) ? Qb : (blockIdx.z == 1) ? Kb : Vb;
    int bx = blockIdx.x, by = blockIdx.y;

    __shared__ short Alds[128][72];   // +8 pad
    __shared__ short Blds[64][72];
    int t = threadIdx.x;
    int wave = t >> 6, lane = t & 63;
    int wr = wave >> 1, wc = wave & 1;
    int lr = t >> 3;              // 0..31
    int lk = (t & 7) << 3;        // 0..56 (8 elems)

    const float* Abase = x + ((size_t)(by * 128 + lr)) * D_MODEL + lk;
    const float* Bbase = B + ((size_t)(bx * 64 + lr)) * D_MODEL + lk;

    int fm = lane & 15;
    int fk = (lane >> 4) << 3;

    f32x4 acc[4][2];
#pragma unroll
    for (int r = 0; r < 4; ++r)
#pragma unroll
        for (int c = 0; c < 2; ++c) acc[r][c] = (f32x4){0.f, 0.f, 0.f, 0.f};

    for (int k0 = 0; k0 < D_MODEL; k0 += 64) {
        pack8(Abase + k0,               &Alds[lr][lk]);
        pack8(Abase + 32 * D_MODEL + k0, &Alds[lr + 32][lk]);
        pack8(Abase + 64 * D_MODEL + k0, &Alds[lr + 64][lk]);
        pack8(Abase + 96 * D_MODEL + k0, &Alds[lr + 96][lk]);
        pack8(Bbase + k0,               &Blds[lr][lk]);
        pack8(Bbase + 32 * D_MODEL + k0, &Blds[lr + 32][lk]);
        __syncthreads();
#pragma unroll
        for (int ks = 0; ks < 64; ks += 32) {
            bf16x8 af[4], bf[2];
#pragma unroll
            for (int r = 0; r < 4; ++r)
                af[r] = *(const bf16x8*)&Alds[wr * 64 + r * 16 + fm][ks + fk];
#pragma unroll
            for (int c = 0; c < 2; ++c)
                bf[c] = *(const bf16x8*)&Blds[wc * 32 + c * 16 + fm][ks + fk];
#pragma unroll
            for (int r = 0; r < 4; ++r)
#pragma unroll
                for (int c = 0; c < 2; ++c)
                    acc[r][c] = __builtin_amdgcn_mfma_f32_16x16x32_bf16(
                        af[r], bf[c], acc[r][c], 0, 0, 0);
        }
        __syncthreads();
    }

    int orow0 = by * 128 + wr * 64 + ((lane >> 4) << 2);
    int ocol0 = bx * 64 + wc * 32 + (lane & 15);
#pragma unroll
    for (int r = 0; r < 4; ++r)
#pragma unroll
        for (int c = 0; c < 2; ++c)
#pragma unroll
            for (int q = 0; q < 4; ++q)
                Cb[(size_t)(orow0 + r * 16 + q) * D_MODEL + ocol0 + c * 16] =
                    f2bf(acc[r][c][q]);
}

// ---------------------------------------------------------------------------
// Sparse attention, two-pass, MFMA-scored. One wave (64 thr) per dst.
// ---------------------------------------------------------------------------
__global__ __launch_bounds__(64) void attn_kernel(
        const unsigned short* __restrict__ Qb, const unsigned short* __restrict__ Kb,
        const unsigned short* __restrict__ Vb,
        const unsigned long long* __restrict__ mask,
        unsigned short* __restrict__ Ob, int n) {
    int dst = blockIdx.x;
    int L = threadIdx.x;
    int wpr = n >> 6;

    __shared__ int nbr[MAXN + 16];
    __shared__ float s_lds[N_HEADS][MAXN];

    // ---- Phase A: neighbor enumeration ----
    unsigned long long w = (L < wpr) ? mask[(size_t)dst * wpr + L] : 0ULL;
    int c = __popcll(w);
    int xs = c;
#pragma unroll
    for (int o = 1; o < 64; o <<= 1) {
        int y = __shfl_up(xs, o, 64);
        if (L >= o) xs += y;
    }
    int pos = xs - c;
    while (w) {
        int b = __builtin_ctzll(w);
        w &= w - 1;
        if (pos < MAXN) nbr[pos] = (L << 6) + b;
        ++pos;
    }
    int cnt = __shfl(xs, 63, 64);
    if (cnt > MAXN) cnt = MAXN;
    int nb = (cnt + 15) & ~15;
    __syncthreads();
    int last = nbr[cnt - 1];
    if (L < nb - cnt) nbr[cnt + L] = last;   // pad; padded scores forced to -1e30
    __syncthreads();

    // per-lane Q fragment (head = L&15, dims (L>>4)*8..+7); zero for cols>=8
    int col = L & 15;
    int kq = L >> 4;
    bf16x8 qf = (bf16x8){0, 0, 0, 0, 0, 0, 0, 0};
    if (col < N_HEADS)
        qf = *(const bf16x8*)(Qb + (size_t)dst * D_MODEL + col * D_HEAD + kq * 8);
    const bf16x8 zf = (bf16x8){0, 0, 0, 0, 0, 0, 0, 0};
    const float inv_scale = 0.17677669529663687f;   // 1/sqrt(32)

    // ---- Phase B: scores via MFMA (head-masked B trick) ----
    for (int b0 = 0; b0 < nb; b0 += 16) {
        int nj = nbr[b0 + col];
        const unsigned short* krow = Kb + (size_t)nj * D_MODEL + kq * 8;
        f32x4 c0 = (f32x4){0.f, 0.f, 0.f, 0.f};
        f32x4 c1 = (f32x4){0.f, 0.f, 0.f, 0.f};
#pragma unroll
        for (int kb = 0; kb < 8; kb += 2) {
            bf16x8 a0 = *(const bf16x8*)(krow + kb * 32);
            bf16x8 a1 = *(const bf16x8*)(krow + kb * 32 + 32);
            bf16x8 bop0 = (col == kb)     ? qf : zf;
            bf16x8 bop1 = (col == kb + 1) ? qf : zf;
            c0 = __builtin_amdgcn_mfma_f32_16x16x32_bf16(a0, bop0, c0, 0, 0, 0);
            c1 = __builtin_amdgcn_mfma_f32_16x16x32_bf16(a1, bop1, c1, 0, 0, 0);
        }
        if (col < N_HEADS) {
            int jr = b0 + kq * 4;
            float4 o;
            float s0 = (c0[0] + c1[0]) * inv_scale;
            float s1 = (c0[1] + c1[1]) * inv_scale;
            float s2 = (c0[2] + c1[2]) * inv_scale;
            float s3 = (c0[3] + c1[3]) * inv_scale;
            o.x = (jr + 0 < cnt) ? s0 : -1e30f;
            o.y = (jr + 1 < cnt) ? s1 : -1e30f;
            o.z = (jr + 2 < cnt) ? s2 : -1e30f;
            o.w = (jr + 3 < cnt) ? s3 : -1e30f;
            *(float4*)&s_lds[col][jr] = o;
        }
    }
    __syncthreads();

    // ---- Phase C: softmax (h = L>>3, 8 lanes per head) ----
    int h = L >> 3, i = L & 7;
    float m = -1e30f;
    for (int j0 = i * 4; j0 < nb; j0 += 32) {
        float4 v = *(const float4*)&s_lds[h][j0];
        m = fmaxf(m, fmaxf(fmaxf(v.x, v.y), fmaxf(v.z, v.w)));
    }
    m = fmaxf(m, __shfl_xor(m, 1, 8));
    m = fmaxf(m, __shfl_xor(m, 2, 8));
    m = fmaxf(m, __shfl_xor(m, 4, 8));
    float l = 0.f;
    for (int j0 = i * 4; j0 < nb; j0 += 32) {
        float4 v = *(const float4*)&s_lds[h][j0];
        float4 e;
        e.x = __expf(v.x - m); e.y = __expf(v.y - m);
        e.z = __expf(v.z - m); e.w = __expf(v.w - m);
        *(float4*)&s_lds[h][j0] = e;
        l += (e.x + e.y) + (e.z + e.w);
    }
    l += __shfl_xor(l, 1, 8);
    l += __shfl_xor(l, 2, 8);
    l += __shfl_xor(l, 4, 8);
    __syncthreads();

    // ---- Phase D: PV accumulate. Lane: head h=L>>3, dims (L&7)*4..+3 ----
    f32x4 acc = (f32x4){0.f, 0.f, 0.f, 0.f};
    const unsigned short* vb = Vb + 4 * L;
    for (int j = 0; j < nb; j += 4) {
        float4 wv = *(const float4*)&s_lds[h][j];
        int j0 = nbr[j], j1 = nbr[j + 1], j2 = nbr[j + 2], j3 = nbr[j + 3];
        uint2 r0 = *(const uint2*)(vb + (size_t)j0 * D_MODEL);
        uint2 r1 = *(const uint2*)(vb + (size_t)j1 * D_MODEL);
        uint2 r2 = *(const uint2*)(vb + (size_t)j2 * D_MODEL);
        uint2 r3 = *(const uint2*)(vb + (size_t)j3 * D_MODEL);
        acc[0] += wv.x * bf2f((unsigned short)(r0.x & 0xffff));
        acc[1] += wv.x * bf2f((unsigned short)(r0.x >> 16));
        acc[2] += wv.x * bf2f((unsigned short)(r0.y & 0xffff));
        acc[3] += wv.x * bf2f((unsigned short)(r0.y >> 16));
        acc[0] += wv.y * bf2f((unsigned short)(r1.x & 0xffff));
        acc[1] += wv.y * bf2f((unsigned short)(r1.x >> 16));
        acc[2] += wv.y * bf2f((unsigned short)(r1.y & 0xffff));
        acc[3] += wv.y * bf2f((unsigned short)(r1.y >> 16));
        acc[0] += wv.z * bf2f((unsigned short)(r2.x & 0xffff));
        acc[1] += wv.z * bf2f((unsigned short)(r2.x >> 16));
        acc[2] += wv.z * bf2f((unsigned short)(r2.y & 0xffff));
        acc[3] += wv.z * bf2f((unsigned short)(r2.y >> 16));
        acc[0] += wv.w * bf2f((unsigned short)(r3.x & 0xffff));
        acc[1] += wv.w * bf2f((unsigned short)(r3.x >> 16));
        acc[2] += wv.w * bf2f((unsigned short)(r3.y & 0xffff));
        acc[3] += wv.w * bf2f((unsigned short)(r3.y >> 16));
    }
    float rl = 1.f / l;
    ushort4 o;
    o.x = f2bf(acc[0] * rl); o.y = f2bf(acc[1] * rl);
    o.z = f2bf(acc[2] * rl); o.w = f2bf(acc[3] * rl);
    *(ushort4*)(Ob + (size_t)dst * D_MODEL + 4 * L) = o;
}

// ---------------------------------------------------------------------------
// Fused output GEMM + residual + bias + LayerNorm.
// BM=64, BN=256 (full row), BK=64. 256 thr = 4 waves; wave w computes rows
// [w*16, w*16+16) x all 256 cols (16 MFMA col-tiles). Epilogue: acc -> LDS,
// per-row wave reduce (mean/var over h = x + proj + bo), normalize, store.
// ---------------------------------------------------------------------------
struct SMemO {
    union {
        struct { short A[64][72]; short B[256][72]; } st;
        float c[64][260];
    };
};

__global__ __launch_bounds__(256) void gemm_o_ln_kernel(
        const unsigned short* __restrict__ Ob, const float* __restrict__ Wo,
        const float* __restrict__ x, const float* __restrict__ bo,
        const float* __restrict__ gamma, const float* __restrict__ beta,
        float* __restrict__ out) {
    __shared__ SMemO sm;
    int by = blockIdx.x;
    int t = threadIdx.x;
    int wave = t >> 6, lane = t & 63;
    int lr = t >> 3;              // 0..31
    int lk = (t & 7) << 3;        // 0..56

    const unsigned short* Abase = Ob + ((size_t)(by * 64 + lr)) * D_MODEL + lk;
    int fm = lane & 15;
    int fk = (lane >> 4) << 3;

    f32x4 acc[16];
#pragma unroll
    for (int ct = 0; ct < 16; ++ct) acc[ct] = (f32x4){0.f, 0.f, 0.f, 0.f};

    for (int k0 = 0; k0 < D_MODEL; k0 += 64) {
        *(uint4*)&sm.st.A[lr][lk]      = *(const uint4*)(Abase + k0);
        *(uint4*)&sm.st.A[lr + 32][lk] = *(const uint4*)(Abase + 32 * D_MODEL + k0);
#pragma unroll
        for (int j = 0; j < 8; ++j)
            pack8(Wo + ((size_t)(lr + 32 * j)) * D_MODEL + k0 + lk,
                  &sm.st.B[lr + 32 * j][lk]);
        __syncthreads();
#pragma unroll
        for (int ks = 0; ks < 64; ks += 32) {
            bf16x8 af = *(const bf16x8*)&sm.st.A[wave * 16 + fm][ks + fk];
#pragma unroll
            for (int ct = 0; ct < 16; ++ct) {
                bf16x8 bf = *(const bf16x8*)&sm.st.B[ct * 16 + fm][ks + fk];
                acc[ct] = __builtin_amdgcn_mfma_f32_16x16x32_bf16(af, bf, acc[ct], 0, 0, 0);
            }
        }
        __syncthreads();
    }

    // scatter acc tiles into LDS row-major c[64][260]
    int rr0 = wave * 16 + ((lane >> 4) << 2);
#pragma unroll
    for (int ct = 0; ct < 16; ++ct)
#pragma unroll
        for (int q = 0; q < 4; ++q)
            sm.c[rr0 + q][ct * 16 + (lane & 15)] = acc[ct][q];
    __syncthreads();

    // LayerNorm: wave w handles rows w*16 .. w*16+15; lane covers 4 cols
    float4 bo4 = *(const float4*)(bo + lane * 4);
    float4 g4  = *(const float4*)(gamma + lane * 4);
    float4 be4 = *(const float4*)(beta + lane * 4);
    for (int rr = 0; rr < 16; ++rr) {
        int r = wave * 16 + rr;
        int grow = by * 64 + r;
        float4 p = *(const float4*)&sm.c[r][lane * 4];
        float4 xv = *(const float4*)(x + (size_t)grow * D_MODEL + lane * 4);
        float hx = p.x + xv.x + bo4.x;
        float hy = p.y + xv.y + bo4.y;
        float hz = p.z + xv.z + bo4.z;
        float hw = p.w + xv.w + bo4.w;
        float s  = (hx + hy) + (hz + hw);
        float s2 = (hx * hx + hy * hy) + (hz * hz + hw * hw);
#pragma unroll
        for (int o = 32; o; o >>= 1) {
            s  += __shfl_xor(s, o, 64);
            s2 += __shfl_xor(s2, o, 64);
        }
        float mu = s * (1.f / 256.f);
        float var = s2 * (1.f / 256.f) - mu * mu;
        float rstd = rsqrtf(var + 1e-5f);
        float4 o4;
        o4.x = (hx - mu) * rstd * g4.x + be4.x;
        o4.y = (hy - mu) * rstd * g4.y + be4.y;
        o4.z = (hz - mu) * rstd * g4.z + be4.z;
        o4.w = (hw - mu) * rstd * g4.w + be4.w;
        *(float4*)(out + (size_t)grow * D_MODEL + lane * 4) = o4;
    }
}

// ---------------------------------------------------------------------------
extern "C" void kernel_launch(void* const* d_in, const int* in_sizes, int n_in,
                              void* d_out, int out_size, void* d_ws, size_t ws_size,
                              hipStream_t stream) {
    const float* x     = (const float*)d_in[0];
    const int*   ei    = (const int*)  d_in[1];
    const float* Wq    = (const float*)d_in[2];
    const float* Wk    = (const float*)d_in[3];
    const float* Wv    = (const float*)d_in[4];
    const float* Wo    = (const float*)d_in[5];
    const float* bo    = (const float*)d_in[6];
    const float* gamma = (const float*)d_in[7];
    const float* beta  = (const float*)d_in[8];
    float* out = (float*)d_out;

    int n = in_sizes[0] / D_MODEL;   // 4096
    int E = in_sizes[1] / 2;         // 131072

    char* ws = (char*)d_ws;
    size_t off = 0;
    unsigned long long* mask = (unsigned long long*)(ws + off);
    size_t mask_bytes = (size_t)n * (n >> 6) * sizeof(unsigned long long);   // 2 MiB
    off += mask_bytes;
    unsigned short* Qb = (unsigned short*)(ws + off); off += (size_t)n * D_MODEL * 2;
    unsigned short* Kb = (unsigned short*)(ws + off); off += (size_t)n * D_MODEL * 2;
    unsigned short* Vb = (unsigned short*)(ws + off); off += (size_t)n * D_MODEL * 2;
    unsigned short* Ob = (unsigned short*)(ws + off); off += (size_t)n * D_MODEL * 2;

    hipMemsetAsync(mask, 0, mask_bytes, stream);
    set_edges_kernel<<<(E + 255) / 256, 256, 0, stream>>>(ei, mask, E, n);

    dim3 gq(D_MODEL / 64, n / 128, 3);
    gemm_qkv_kernel<<<gq, 256, 0, stream>>>(x, Wq, Wk, Wv, Qb, Kb, Vb);

    attn_kernel<<<n, 64, 0, stream>>>(Qb, Kb, Vb, mask, Ob, n);

    gemm_o_ln_kernel<<<n / 64, 256, 0, stream>>>(Ob, Wo, x, bo, gamma, beta, out);
}

// Round 5
// 113.798 us; speedup vs baseline: 1.1856x; 1.1856x over previous
//
#include <hip/hip_runtime.h>

#define D_MODEL 256
#define N_HEADS 8
#define D_HEAD 32
#define MAXN 192   // max neighbors/row; Poisson(32), max over 4096 rows ~60

typedef __attribute__((ext_vector_type(8))) short bf16x8;
typedef __attribute__((ext_vector_type(4))) float f32x4;

__device__ __forceinline__ unsigned short f2bf(float f) {
    union { float f; unsigned int u; } v; v.f = f;
    unsigned int r = v.u + 0x7fff + ((v.u >> 16) & 1);   // RNE
    return (unsigned short)(r >> 16);
}
__device__ __forceinline__ float bf2f(unsigned short u) {
    union { unsigned int u; float f; } v; v.u = ((unsigned int)u) << 16;
    return v.f;
}

// ---------------------------------------------------------------------------
// prep: fp32->bf16 converts (x + 4 weights) AND mask init (zeros + diagonal).
// Replaces memset + convert; set_edges only adds edge bits afterwards.
// ---------------------------------------------------------------------------
__global__ void prep_kernel(const float* __restrict__ x,
                            const float* __restrict__ W0, const float* __restrict__ W1,
                            const float* __restrict__ W2, const float* __restrict__ W3,
                            unsigned short* __restrict__ xb,
                            unsigned short* __restrict__ O0, unsigned short* __restrict__ O1,
                            unsigned short* __restrict__ O2, unsigned short* __restrict__ O3,
                            unsigned long long* __restrict__ mask, int n) {
    const int XV = (4096 * 256) / 4;          // 262144 float4s of x
    int i = blockIdx.x * blockDim.x + threadIdx.x;

    // mask init: n * wpr words (4096*64 = 262144)
    int wpr = n >> 6;
    int mwords = n * wpr;
    if (i < mwords) {
        int row = i >> 6;                     // wpr == 64
        int w = i & 63;
        mask[i] = (w == (row >> 6)) ? (1ULL << (row & 63)) : 0ULL;
    }

    const float* src;
    unsigned short* dst;
    int k;
    if (i < XV) {
        src = x; dst = xb; k = i;
    } else {
        int i2 = i - XV;                      // < 4*16384
        if (i2 >= 4 * 16384) return;
        int z = i2 >> 14;
        k = i2 & 16383;
        src = (z == 0) ? W0 : (z == 1) ? W1 : (z == 2) ? W2 : W3;
        dst = (z == 0) ? O0 : (z == 1) ? O1 : (z == 2) ? O2 : O3;
    }
    float4 v = *(const float4*)(src + (size_t)k * 4);
    ushort4 o;
    o.x = f2bf(v.x); o.y = f2bf(v.y); o.z = f2bf(v.z); o.w = f2bf(v.w);
    *(ushort4*)(dst + (size_t)k * 4) = o;
}

// ---------------------------------------------------------------------------
// Fused: QKV GEMM (blocks 0..NGEMM-1) + edge-mask atomicOr (blocks NGEMM..).
// GEMM: C = xb @ W^T (bf16 in, bf16 out). BM=128, BN=64, BK=64,
// 256 thr = 4 waves, each wave 64x32 (4x2 MFMA tiles).
// ---------------------------------------------------------------------------
#define NGEMM 384   // 4 bx * 32 by * 3 z

__global__ __launch_bounds__(256) void qkv_edges_kernel(
        const unsigned short* __restrict__ xb,
        const unsigned short* __restrict__ Wq, const unsigned short* __restrict__ Wk,
        const unsigned short* __restrict__ Wv,
        unsigned short* __restrict__ Qb, unsigned short* __restrict__ Kb,
        unsigned short* __restrict__ Vb,
        const int* __restrict__ ei, unsigned long long* __restrict__ mask,
        int E, int n) {
    int blk = blockIdx.x;
    if (blk >= NGEMM) {
        int e = (blk - NGEMM) * 256 + threadIdx.x;
        if (e < E) {
            int src = ei[e];
            int dst = ei[E + e];
            int wpr = n >> 6;
            atomicOr(&mask[(size_t)dst * wpr + (src >> 6)], 1ULL << (src & 63));
        }
        return;
    }
    int z = blk >> 7;                // 0..2
    int r = blk & 127;
    int by = r >> 2, bx = r & 3;
    const unsigned short* B = (z == 0) ? Wq : (z == 1) ? Wk : Wv;
    unsigned short* Cb = (z == 0) ? Qb : (z == 1) ? Kb : Vb;

    __shared__ short Alds[128][72];   // +8 pad
    __shared__ short Blds[64][72];
    int t = threadIdx.x;
    int wave = t >> 6, lane = t & 63;
    int wr = wave >> 1, wc = wave & 1;
    int lr = t >> 3;
    int lk = (t & 7) << 3;

    const unsigned short* Abase = xb + ((size_t)(by * 128 + lr)) * D_MODEL + lk;
    const unsigned short* Bbase = B + ((size_t)(bx * 64 + lr)) * D_MODEL + lk;

    int fm = lane & 15;
    int fk = (lane >> 4) << 3;

    f32x4 acc[4][2];
#pragma unroll
    for (int rr = 0; rr < 4; ++rr)
#pragma unroll
        for (int c = 0; c < 2; ++c) acc[rr][c] = (f32x4){0.f, 0.f, 0.f, 0.f};

    for (int k0 = 0; k0 < D_MODEL; k0 += 64) {
        *(uint4*)&Alds[lr][lk]      = *(const uint4*)(Abase + k0);
        *(uint4*)&Alds[lr + 32][lk] = *(const uint4*)(Abase + 32 * D_MODEL + k0);
        *(uint4*)&Alds[lr + 64][lk] = *(const uint4*)(Abase + 64 * D_MODEL + k0);
        *(uint4*)&Alds[lr + 96][lk] = *(const uint4*)(Abase + 96 * D_MODEL + k0);
        *(uint4*)&Blds[lr][lk]      = *(const uint4*)(Bbase + k0);
        *(uint4*)&Blds[lr + 32][lk] = *(const uint4*)(Bbase + 32 * D_MODEL + k0);
        __syncthreads();
#pragma unroll
        for (int ks = 0; ks < 64; ks += 32) {
            bf16x8 af[4], bf[2];
#pragma unroll
            for (int rr = 0; rr < 4; ++rr)
                af[rr] = *(const bf16x8*)&Alds[wr * 64 + rr * 16 + fm][ks + fk];
#pragma unroll
            for (int c = 0; c < 2; ++c)
                bf[c] = *(const bf16x8*)&Blds[wc * 32 + c * 16 + fm][ks + fk];
#pragma unroll
            for (int rr = 0; rr < 4; ++rr)
#pragma unroll
                for (int c = 0; c < 2; ++c)
                    acc[rr][c] = __builtin_amdgcn_mfma_f32_16x16x32_bf16(
                        af[rr], bf[c], acc[rr][c], 0, 0, 0);
        }
        __syncthreads();
    }

    int orow0 = by * 128 + wr * 64 + ((lane >> 4) << 2);
    int ocol0 = bx * 64 + wc * 32 + (lane & 15);
#pragma unroll
    for (int rr = 0; rr < 4; ++rr)
#pragma unroll
        for (int c = 0; c < 2; ++c)
#pragma unroll
            for (int q = 0; q < 4; ++q)
                Cb[(size_t)(orow0 + rr * 16 + q) * D_MODEL + ocol0 + c * 16] =
                    f2bf(acc[rr][c][q]);
}

// ---------------------------------------------------------------------------
// Sparse attention, two-pass, MFMA-scored. One wave (64 thr) per dst.
// ---------------------------------------------------------------------------
__global__ __launch_bounds__(64) void attn_kernel(
        const unsigned short* __restrict__ Qb, const unsigned short* __restrict__ Kb,
        const unsigned short* __restrict__ Vb,
        const unsigned long long* __restrict__ mask,
        unsigned short* __restrict__ Ob, int n) {
    int dst = blockIdx.x;
    int L = threadIdx.x;
    int wpr = n >> 6;

    __shared__ int nbr[MAXN + 16];
    __shared__ float s_lds[N_HEADS][MAXN];

    // ---- Phase A: neighbor enumeration ----
    unsigned long long w = (L < wpr) ? mask[(size_t)dst * wpr + L] : 0ULL;
    int c = __popcll(w);
    int xs = c;
#pragma unroll
    for (int o = 1; o < 64; o <<= 1) {
        int y = __shfl_up(xs, o, 64);
        if (L >= o) xs += y;
    }
    int pos = xs - c;
    while (w) {
        int b = __builtin_ctzll(w);
        w &= w - 1;
        if (pos < MAXN) nbr[pos] = (L << 6) + b;
        ++pos;
    }
    int cnt = __shfl(xs, 63, 64);
    if (cnt > MAXN) cnt = MAXN;
    int nb = (cnt + 15) & ~15;
    __syncthreads();
    int last = nbr[cnt - 1];
    if (L < nb - cnt) nbr[cnt + L] = last;   // pad; padded scores forced to -1e30
    __syncthreads();

    // per-lane Q fragment (head = L&15, dims (L>>4)*8..+7); zero for cols>=8
    int col = L & 15;
    int kq = L >> 4;
    bf16x8 qf = (bf16x8){0, 0, 0, 0, 0, 0, 0, 0};
    if (col < N_HEADS)
        qf = *(const bf16x8*)(Qb + (size_t)dst * D_MODEL + col * D_HEAD + kq * 8);
    const bf16x8 zf = (bf16x8){0, 0, 0, 0, 0, 0, 0, 0};
    const float inv_scale = 0.17677669529663687f;   // 1/sqrt(32)

    // ---- Phase B: scores via MFMA (head-masked B trick) ----
    for (int b0 = 0; b0 < nb; b0 += 16) {
        int nj = nbr[b0 + col];
        const unsigned short* krow = Kb + (size_t)nj * D_MODEL + kq * 8;
        f32x4 c0 = (f32x4){0.f, 0.f, 0.f, 0.f};
        f32x4 c1 = (f32x4){0.f, 0.f, 0.f, 0.f};
#pragma unroll
        for (int kb = 0; kb < 8; kb += 2) {
            bf16x8 a0 = *(const bf16x8*)(krow + kb * 32);
            bf16x8 a1 = *(const bf16x8*)(krow + kb * 32 + 32);
            bf16x8 bop0 = (col == kb)     ? qf : zf;
            bf16x8 bop1 = (col == kb + 1) ? qf : zf;
            c0 = __builtin_amdgcn_mfma_f32_16x16x32_bf16(a0, bop0, c0, 0, 0, 0);
            c1 = __builtin_amdgcn_mfma_f32_16x16x32_bf16(a1, bop1, c1, 0, 0, 0);
        }
        if (col < N_HEADS) {
            int jr = b0 + kq * 4;
            float4 o;
            float s0 = (c0[0] + c1[0]) * inv_scale;
            float s1 = (c0[1] + c1[1]) * inv_scale;
            float s2 = (c0[2] + c1[2]) * inv_scale;
            float s3 = (c0[3] + c1[3]) * inv_scale;
            o.x = (jr + 0 < cnt) ? s0 : -1e30f;
            o.y = (jr + 1 < cnt) ? s1 : -1e30f;
            o.z = (jr + 2 < cnt) ? s2 : -1e30f;
            o.w = (jr + 3 < cnt) ? s3 : -1e30f;
            *(float4*)&s_lds[col][jr] = o;
        }
    }
    __syncthreads();

    // ---- Phase C: softmax (h = L>>3, 8 lanes per head) ----
    int h = L >> 3, i = L & 7;
    float m = -1e30f;
    for (int j0 = i * 4; j0 < nb; j0 += 32) {
        float4 v = *(const float4*)&s_lds[h][j0];
        m = fmaxf(m, fmaxf(fmaxf(v.x, v.y), fmaxf(v.z, v.w)));
    }
    m = fmaxf(m, __shfl_xor(m, 1, 8));
    m = fmaxf(m, __shfl_xor(m, 2, 8));
    m = fmaxf(m, __shfl_xor(m, 4, 8));
    float l = 0.f;
    for (int j0 = i * 4; j0 < nb; j0 += 32) {
        float4 v = *(const float4*)&s_lds[h][j0];
        float4 e;
        e.x = __expf(v.x - m); e.y = __expf(v.y - m);
        e.z = __expf(v.z - m); e.w = __expf(v.w - m);
        *(float4*)&s_lds[h][j0] = e;
        l += (e.x + e.y) + (e.z + e.w);
    }
    l += __shfl_xor(l, 1, 8);
    l += __shfl_xor(l, 2, 8);
    l += __shfl_xor(l, 4, 8);
    __syncthreads();

    // ---- Phase D: PV accumulate. Lane: head h=L>>3, dims (L&7)*4..+3 ----
    f32x4 acc = (f32x4){0.f, 0.f, 0.f, 0.f};
    const unsigned short* vb = Vb + 4 * L;
    for (int j = 0; j < nb; j += 4) {
        float4 wv = *(const float4*)&s_lds[h][j];
        int j0 = nbr[j], j1 = nbr[j + 1], j2 = nbr[j + 2], j3 = nbr[j + 3];
        uint2 r0 = *(const uint2*)(vb + (size_t)j0 * D_MODEL);
        uint2 r1 = *(const uint2*)(vb + (size_t)j1 * D_MODEL);
        uint2 r2 = *(const uint2*)(vb + (size_t)j2 * D_MODEL);
        uint2 r3 = *(const uint2*)(vb + (size_t)j3 * D_MODEL);
        acc[0] += wv.x * bf2f((unsigned short)(r0.x & 0xffff));
        acc[1] += wv.x * bf2f((unsigned short)(r0.x >> 16));
        acc[2] += wv.x * bf2f((unsigned short)(r0.y & 0xffff));
        acc[3] += wv.x * bf2f((unsigned short)(r0.y >> 16));
        acc[0] += wv.y * bf2f((unsigned short)(r1.x & 0xffff));
        acc[1] += wv.y * bf2f((unsigned short)(r1.x >> 16));
        acc[2] += wv.y * bf2f((unsigned short)(r1.y & 0xffff));
        acc[3] += wv.y * bf2f((unsigned short)(r1.y >> 16));
        acc[0] += wv.z * bf2f((unsigned short)(r2.x & 0xffff));
        acc[1] += wv.z * bf2f((unsigned short)(r2.x >> 16));
        acc[2] += wv.z * bf2f((unsigned short)(r2.y & 0xffff));
        acc[3] += wv.z * bf2f((unsigned short)(r2.y >> 16));
        acc[0] += wv.w * bf2f((unsigned short)(r3.x & 0xffff));
        acc[1] += wv.w * bf2f((unsigned short)(r3.x >> 16));
        acc[2] += wv.w * bf2f((unsigned short)(r3.y & 0xffff));
        acc[3] += wv.w * bf2f((unsigned short)(r3.y >> 16));
    }
    float rl = 1.f / l;
    ushort4 o;
    o.x = f2bf(acc[0] * rl); o.y = f2bf(acc[1] * rl);
    o.z = f2bf(acc[2] * rl); o.w = f2bf(acc[3] * rl);
    *(ushort4*)(Ob + (size_t)dst * D_MODEL + 4 * L) = o;
}

// ---------------------------------------------------------------------------
// Fused output GEMM + residual + bias + LayerNorm.
// BM=32, BN=256 (full row), BK=64 -> 128 blocks (fixes R4's 64-block mistake).
// 256 thr = 4 waves; wave (rt = w>>1, cq = w&1) computes rows rt*16..+16,
// cols cq*128..+128 (8 col-tiles). Epilogue: acc -> LDS (union), per-row
// reduce mean/var of h = proj + x + bo, normalize, store fp32.
// ---------------------------------------------------------------------------
struct SMemO {
    union {
        struct { short A[32][72]; short B[256][72]; } st;
        float c[32][260];
    };
};

__global__ __launch_bounds__(256) void gemm_o_ln_kernel(
        const unsigned short* __restrict__ Ob, const unsigned short* __restrict__ Wob,
        const float* __restrict__ x, const float* __restrict__ bo,
        const float* __restrict__ gamma, const float* __restrict__ beta,
        float* __restrict__ out) {
    __shared__ SMemO sm;
    int by = blockIdx.x;
    int t = threadIdx.x;
    int wave = t >> 6, lane = t & 63;
    int rt = wave >> 1, cq = wave & 1;
    int lr = t >> 3;              // 0..31
    int lk = (t & 7) << 3;        // 0..56

    const unsigned short* Abase = Ob + ((size_t)(by * 32 + lr)) * D_MODEL + lk;
    int fm = lane & 15;
    int fk = (lane >> 4) << 3;

    f32x4 acc[8];
#pragma unroll
    for (int ct = 0; ct < 8; ++ct) acc[ct] = (f32x4){0.f, 0.f, 0.f, 0.f};

    for (int k0 = 0; k0 < D_MODEL; k0 += 64) {
        *(uint4*)&sm.st.A[lr][lk] = *(const uint4*)(Abase + k0);
#pragma unroll
        for (int j = 0; j < 8; ++j)
            *(uint4*)&sm.st.B[lr + 32 * j][lk] =
                *(const uint4*)(Wob + ((size_t)(lr + 32 * j)) * D_MODEL + k0 + lk);
        __syncthreads();
#pragma unroll
        for (int ks = 0; ks < 64; ks += 32) {
            bf16x8 af = *(const bf16x8*)&sm.st.A[rt * 16 + fm][ks + fk];
#pragma unroll
            for (int ct = 0; ct < 8; ++ct) {
                bf16x8 bf = *(const bf16x8*)&sm.st.B[cq * 128 + ct * 16 + fm][ks + fk];
                acc[ct] = __builtin_amdgcn_mfma_f32_16x16x32_bf16(af, bf, acc[ct], 0, 0, 0);
            }
        }
        __syncthreads();
    }

    // scatter acc tiles into LDS row-major c[32][260] (aliases staging; safe
    // because k-loop's final __syncthreads precedes these writes)
    int rr0 = rt * 16 + ((lane >> 4) << 2);
#pragma unroll
    for (int ct = 0; ct < 8; ++ct)
#pragma unroll
        for (int q = 0; q < 4; ++q)
            sm.c[rr0 + q][cq * 128 + ct * 16 + (lane & 15)] = acc[ct][q];
    __syncthreads();

    // LayerNorm: wave w handles rows w*8 .. w*8+7; lane covers 4 cols
    float4 bo4 = *(const float4*)(bo + lane * 4);
    float4 g4  = *(const float4*)(gamma + lane * 4);
    float4 be4 = *(const float4*)(beta + lane * 4);
#pragma unroll
    for (int rr = 0; rr < 8; ++rr) {
        int r = wave * 8 + rr;
        int grow = by * 32 + r;
        float4 p = *(const float4*)&sm.c[r][lane * 4];
        float4 xv = *(const float4*)(x + (size_t)grow * D_MODEL + lane * 4);
        float hx = p.x + xv.x + bo4.x;
        float hy = p.y + xv.y + bo4.y;
        float hz = p.z + xv.z + bo4.z;
        float hw = p.w + xv.w + bo4.w;
        float s  = (hx + hy) + (hz + hw);
        float s2 = (hx * hx + hy * hy) + (hz * hz + hw * hw);
#pragma unroll
        for (int o = 32; o; o >>= 1) {
            s  += __shfl_xor(s, o, 64);
            s2 += __shfl_xor(s2, o, 64);
        }
        float mu = s * (1.f / 256.f);
        float var = s2 * (1.f / 256.f) - mu * mu;
        float rstd = rsqrtf(var + 1e-5f);
        float4 o4;
        o4.x = (hx - mu) * rstd * g4.x + be4.x;
        o4.y = (hy - mu) * rstd * g4.y + be4.y;
        o4.z = (hz - mu) * rstd * g4.z + be4.z;
        o4.w = (hw - mu) * rstd * g4.w + be4.w;
        *(float4*)(out + (size_t)grow * D_MODEL + lane * 4) = o4;
    }
}

// ---------------------------------------------------------------------------
extern "C" void kernel_launch(void* const* d_in, const int* in_sizes, int n_in,
                              void* d_out, int out_size, void* d_ws, size_t ws_size,
                              hipStream_t stream) {
    const float* x     = (const float*)d_in[0];
    const int*   ei    = (const int*)  d_in[1];
    const float* Wq    = (const float*)d_in[2];
    const float* Wk    = (const float*)d_in[3];
    const float* Wv    = (const float*)d_in[4];
    const float* Wo    = (const float*)d_in[5];
    const float* bo    = (const float*)d_in[6];
    const float* gamma = (const float*)d_in[7];
    const float* beta  = (const float*)d_in[8];
    float* out = (float*)d_out;

    int n = in_sizes[0] / D_MODEL;   // 4096
    int E = in_sizes[1] / 2;         // 131072

    char* ws = (char*)d_ws;
    size_t off = 0;
    unsigned long long* mask = (unsigned long long*)(ws + off);
    off += (size_t)n * (n >> 6) * sizeof(unsigned long long);          // 2 MiB
    unsigned short* xb  = (unsigned short*)(ws + off); off += (size_t)n * D_MODEL * 2;
    unsigned short* Wqb = (unsigned short*)(ws + off); off += D_MODEL * D_MODEL * 2;
    unsigned short* Wkb = (unsigned short*)(ws + off); off += D_MODEL * D_MODEL * 2;
    unsigned short* Wvb = (unsigned short*)(ws + off); off += D_MODEL * D_MODEL * 2;
    unsigned short* Wob = (unsigned short*)(ws + off); off += D_MODEL * D_MODEL * 2;
    unsigned short* Qb  = (unsigned short*)(ws + off); off += (size_t)n * D_MODEL * 2;
    unsigned short* Kb  = (unsigned short*)(ws + off); off += (size_t)n * D_MODEL * 2;
    unsigned short* Vb  = (unsigned short*)(ws + off); off += (size_t)n * D_MODEL * 2;
    unsigned short* Ob  = (unsigned short*)(ws + off); off += (size_t)n * D_MODEL * 2;

    // 1) prep: converts + mask init (diag), 1280 blocks covers max(327680 cv, 262144 mask)/256
    prep_kernel<<<1280, 256, 0, stream>>>(x, Wq, Wk, Wv, Wo,
                                          xb, Wqb, Wkb, Wvb, Wob, mask, n);

    // 2) fused QKV GEMM + edge scatter
    int edge_blocks = (E + 255) / 256;       // 512
    qkv_edges_kernel<<<NGEMM + edge_blocks, 256, 0, stream>>>(
        xb, Wqb, Wkb, Wvb, Qb, Kb, Vb, ei, mask, E, n);

    // 3) sparse attention
    attn_kernel<<<n, 64, 0, stream>>>(Qb, Kb, Vb, mask, Ob, n);

    // 4) output GEMM + residual + LayerNorm
    gemm_o_ln_kernel<<<n / 32, 256, 0, stream>>>(Ob, Wob, x, bo, gamma, beta, out);
}